// Round 6
// baseline (21104.500 us; speedup 1.0000x reference)
//
#include <hip/hip_runtime.h>
#include <cstdint>
#include <cstddef>

// Problem constants
#define BB 32
#define TT 1024
#define DD 512
#define HH 512
#define NBLK 128           // persistent blocks: 64 per direction, 8 cols each

typedef __bf16 bf16x8 __attribute__((ext_vector_type(8)));
typedef float  f32x4  __attribute__((ext_vector_type(4)));
typedef unsigned long long u64;

// ws layout (bytes):
//   hfrag : u64[2 dir][2 buf][2 ni][16 s][64 lane][4 p] {stamp:32|2bf16:32}
//           = 2*2*2*16*64*4*8                            = 262144 B @ 0
//   xhat  : float[2 pass][TT][BB]  (epilogue only)       = 262144 B @ 262144
//   xs    : u64  [TT][BB] stamped x_hat, write-once      = 262144 B @ 524288
#define HFRAG_OFF 0
#define XHAT_OFF  262144
#define XS_OFF    524288

#define AT_LOAD(p)     __hip_atomic_load((p),      __ATOMIC_RELAXED, __HIP_MEMORY_SCOPE_AGENT)
#define AT_STORE(p, v) __hip_atomic_store((p), (v), __ATOMIC_RELAXED, __HIP_MEMORY_SCOPE_AGENT)

__device__ __forceinline__ float sigm(float x) {
    return 1.f / (1.f + __expf(-x));
}
__device__ __forceinline__ float tanh_fast(float x) {
    x = fminf(15.f, fmaxf(-15.f, x));
    float e = __expf(2.f * x);
    return (e - 1.f) / (e + 1.f);
}

// Dataflow design (no barriers at all):
// Round g (g = 2t+pass+1, g = 1..2048) consumes h fragments stamped g-1 from
// buffer (g-1)&1 and publishes h stamped g into buffer g&1. Each u64 slot is
// written by exactly one lane per use (single 8B atomic store carries stamp
// and data together -> no store-ack wait, no flag, no barrier). Consumers
// spin-reload until stamp == g-1. Slot reuse is safe: a producer overwrites
// stamp g-1 with g+1 only after it consumed stamp g from ALL waves of its
// (dir,ni) group, which implies every reader of the slot already consumed
// g-1 (a wave publishes g only after consuming g-1). '==' match also means
// a reader can never miss its stamp. 0xAAAAAAAA ws-poison = negative stamp,
// never matches, so no init barrier is needed either: producers store
// stamp-0 zeros at start and round-1 consumers spin until they land.

__global__ __launch_bounds__(256, 1) void lstm_persistent(
    const float* __restrict__ u,
    const float* __restrict__ wih_f, const float* __restrict__ whh_f,
    const float* __restrict__ bih_f, const float* __restrict__ bhh_f,
    const float* __restrict__ wih_b, const float* __restrict__ whh_b,
    const float* __restrict__ bih_b, const float* __restrict__ bhh_b,
    u64* __restrict__ hfrag, float* __restrict__ xhat,
    u64* __restrict__ xs)
{
    const int bid  = blockIdx.x;
    const int dir  = bid >> 6;        // 0 = forward cell, 1 = backward cell
    const int kb   = bid & 63;
    const int k0   = kb << 3;         // 8 hidden columns per block
    const int tid  = threadIdx.x;
    const int wid  = tid >> 6;        // 4 waves: (mi = wid>>1, ni = wid&1)
    const int mi   = wid >> 1;        // col-group half (4 cols each)
    const int ni   = wid & 1;         // batch half (16 batches each)
    const int lane = tid & 63;
    const int quad = lane >> 4;
    const int l16  = lane & 15;

    const float* wih = dir ? wih_b : wih_f;
    const float* whh = dir ? whh_b : whh_f;
    const float* bih = dir ? bih_b : bih_f;
    const float* bhh = dir ? bhh_b : bhh_f;

    // ---- A-fragments (weights) pinned in registers for the whole kernel ----
    // A-frag layout: lane holds A[m = lane&15][k = quad*8 + i], i = 0..7
    // wave's M rows: m -> global gate row j = (m>>2)*HH + (k0 + 4*mi) + (m&3)
    bf16x8 wihF[16], whhF[16];
    {
        const int jg = (l16 >> 2) * HH + (k0 + 4 * mi) + (l16 & 3);
        #pragma unroll
        for (int s = 0; s < 16; ++s) {
            const float* p = wih + (size_t)jg * DD + s * 32 + quad * 8;
            const float* q = whh + (size_t)jg * HH + s * 32 + quad * 8;
            bf16x8 a, b;
            #pragma unroll
            for (int i = 0; i < 8; ++i) { a[i] = (__bf16)p[i]; b[i] = (__bf16)q[i]; }
            wihF[s] = a;
            whhF[s] = b;
        }
    }

    // ---- per-lane cell: (kc = k0 + 4*mi + quad, bc = ni*16 + l16) ----
    const int kc = k0 + 4 * mi + quad;
    const int bc = ni * 16 + l16;

    // rowsum(W_ih) from the frags (bf16-rounded terms == what the MFMA uses)
    float rsv[4], biasv[4];
    {
        float rs = 0.f;
        #pragma unroll
        for (int s = 0; s < 16; ++s)
            #pragma unroll
            for (int i = 0; i < 8; ++i) rs += (float)wihF[s][i];
        rs += __shfl_xor(rs, 16);
        rs += __shfl_xor(rs, 32);      // lane l16 holds rowsum of wave row l16
        #pragma unroll
        for (int g = 0; g < 4; ++g) {
            rsv[g]   = __shfl(rs, g * 4 + quad);   // row j = g*HH + kc
            const int j = g * HH + kc;
            biasv[g] = bih[j] + bhh[j];
        }
    }

    // ---- h slot addressing ----
    // u64 idx = ((((dir*2+buf)*2+ni)*16 + s)*64 + lane)*4 + p
    // slot (s, lane=q*16+n, p) holds cols {s*32+q*8+2p, +1}, batch ni*16+n.
    const int swq = kc >> 5, qw = (kc >> 3) & 3, pw = (kc & 7) >> 1;
    const int wr0 = ((((dir * 2 + 0) * 2 + ni) * 16 + swq) * 64 + (qw * 16 + l16)) * 4 + pw;
    const int wr1 = wr0 + 8192;                  // buf1 = +2*16*64*4
    const int rb0 = ((dir * 2 + 0) * 2 + ni) * 4096;   // read base, buf0
    const int rb1 = rb0 + 8192;                         // read base, buf1

    // stamp-0 zero-init of buffer 0 (each quad-even lane owns one slot)
    if (!(quad & 1)) AT_STORE(&hfrag[wr0], (u64)0);

    __shared__ __align__(16) float gbuf[4][16][20];  // wave-private gate transpose

    // input-side GEMM on u_t (plain cached loads; off the critical chain)
    auto ugemm = [&](int t) -> f32x4 {
        f32x4 a0 = (f32x4){0.f, 0.f, 0.f, 0.f};
        f32x4 a1 = (f32x4){0.f, 0.f, 0.f, 0.f};
        const float* ub = u + (size_t)bc * (TT * DD) + (size_t)t * DD + quad * 8;
        #pragma unroll
        for (int s = 0; s < 16; ++s) {
            const float4* p = (const float4*)(ub + s * 32);
            float4 x0 = p[0], x1 = p[1];
            bf16x8 uf;
            uf[0] = (__bf16)x0.x; uf[1] = (__bf16)x0.y;
            uf[2] = (__bf16)x0.z; uf[3] = (__bf16)x0.w;
            uf[4] = (__bf16)x1.x; uf[5] = (__bf16)x1.y;
            uf[6] = (__bf16)x1.z; uf[7] = (__bf16)x1.w;
            if (s & 1) a1 = __builtin_amdgcn_mfma_f32_16x16x32_bf16(wihF[s], uf, a1, 0, 0, 0);
            else       a0 = __builtin_amdgcn_mfma_f32_16x16x32_bf16(wihF[s], uf, a0, 0, 0, 0);
        }
        return a0 + a1;
    };

    f32x4 gih = ugemm(0);
    f32x4 gnext = gih;
    float c = 0.f;

    for (int t = 0; t < TT; ++t) {
        #pragma unroll 1
        for (int pass = 0; pass < 2; ++pass) {
            const int g  = 2 * t + pass + 1;    // round number
            const int st = g - 1;               // stamp we consume
            const u64* rp = hfrag + ((g & 1) ? rb0 : rb1);

            // prefetch the full K=512 B-fragment (64 stamped u64s)
            u64 hv[64];
            #pragma unroll
            for (int s = 0; s < 16; ++s)
                #pragma unroll
                for (int p = 0; p < 4; ++p)
                    hv[s * 4 + p] = AT_LOAD(&rp[(s * 64 + lane) * 4 + p]);

            f32x4 acc0 = gih;
            f32x4 acc1 = (f32x4){0.f, 0.f, 0.f, 0.f};
            #pragma unroll
            for (int s = 0; s < 16; ++s) {
                // spin until this step's 4 slots carry stamp g-1 (wave-wide)
                for (;;) {
                    bool ok = ((int)(hv[s * 4 + 0] >> 32) == st) &
                              ((int)(hv[s * 4 + 1] >> 32) == st) &
                              ((int)(hv[s * 4 + 2] >> 32) == st) &
                              ((int)(hv[s * 4 + 3] >> 32) == st);
                    if (__all(ok)) break;
                    #pragma unroll
                    for (int p = 0; p < 4; ++p)
                        hv[s * 4 + p] = AT_LOAD(&rp[(s * 64 + lane) * 4 + p]);
                }
                union { unsigned w[4]; bf16x8 v; } f;
                f.w[0] = (unsigned)hv[s * 4 + 0];
                f.w[1] = (unsigned)hv[s * 4 + 1];
                f.w[2] = (unsigned)hv[s * 4 + 2];
                f.w[3] = (unsigned)hv[s * 4 + 3];
                if (s & 1) acc1 = __builtin_amdgcn_mfma_f32_16x16x32_bf16(whhF[s], f.v, acc1, 0, 0, 0);
                else       acc0 = __builtin_amdgcn_mfma_f32_16x16x32_bf16(whhF[s], f.v, acc0, 0, 0, 0);
            }
            f32x4 acc = acc0 + acc1;

            // pass-1 scalar feedback from the stamped write-once x_hat stream
            float xc = 0.f;
            if (pass) {
                u64 v = AT_LOAD(&xs[t * BB + bc]);
                while ((int)(v >> 32) < 1)
                    v = AT_LOAD(&xs[t * BB + bc]);
                xc = __builtin_bit_cast(float, (unsigned)v);
            }

            // D-layout -> per-cell gates, wave-private LDS (wave-synchronous,
            // same-wave ds ordering: no __syncthreads needed)
            float4 gw; gw.x = acc[0]; gw.y = acc[1]; gw.z = acc[2]; gw.w = acc[3];
            *(float4*)&gbuf[wid][l16][quad * 4] = gw;
            __builtin_amdgcn_wave_barrier();
            float gI = gbuf[wid][l16][ 0 + quad] + biasv[0] + xc * rsv[0];
            float gF = gbuf[wid][l16][ 4 + quad] + biasv[1] + xc * rsv[1];
            float gG = gbuf[wid][l16][ 8 + quad] + biasv[2] + xc * rsv[2];
            float gO = gbuf[wid][l16][12 + quad] + biasv[3] + xc * rsv[3];

            float ig = sigm(gI), fg = sigm(gF), gg = tanh_fast(gG), og = sigm(gO);
            c = fg * c + ig * gg;
            float h = og * tanh_fast(c);

            // publish h stamped g into buffer g&1 (single u64 atomic store,
            // no ack wait — consumers poll the stamp)
            float hp = __shfl_xor(h, 16);
            if (dir == 1 && kc == (HH - 1)) {
                AT_STORE(&xhat[pass * (TT * BB) + t * BB + bc], h);  // epilogue copy
                if (pass == 0)
                    AT_STORE(&xs[t * BB + bc],
                             ((u64)1u << 32) | (u64)__builtin_bit_cast(unsigned, h));
            }
            if (!(quad & 1)) {
                unsigned lo = (unsigned)__builtin_bit_cast(unsigned short, (__bf16)h);
                unsigned hi = (unsigned)__builtin_bit_cast(unsigned short, (__bf16)hp);
                u64 out = ((u64)(unsigned)g << 32) | (u64)(lo | (hi << 16));
                AT_STORE(&hfrag[(g & 1) ? wr1 : wr0], out);
            }

            // next timestep's input GEMM overlaps the stores' flight time
            if (pass == 1 && t + 1 < TT)
                gnext = ugemm(t + 1);
        }
        gih = gnext;
    }
}

__global__ void epilogue(const float* __restrict__ u, const float* __restrict__ xhat,
                         float* __restrict__ out)
{
    const int i = blockIdx.x * blockDim.x + threadIdx.x;   // over float4 groups
    const float4 uv = ((const float4*)u)[i];
    const int bt = i >> 7;             // 128 float4 per (b,t)
    const int t = bt & (TT - 1);
    const int b = bt >> 10;
    const float s = 0.5f * (xhat[t * BB + b] + xhat[TT * BB + t * BB + b]);
    float4 o;
    o.x = 1.5f * uv.x + s;
    o.y = 1.5f * uv.y + s;
    o.z = 1.5f * uv.z + s;
    o.w = 1.5f * uv.w + s;
    ((float4*)out)[i] = o;
}

extern "C" void kernel_launch(void* const* d_in, const int* in_sizes, int n_in,
                              void* d_out, int out_size, void* d_ws, size_t ws_size,
                              hipStream_t stream) {
    const float* u     = (const float*)d_in[0];
    const float* wih_f = (const float*)d_in[1];
    const float* whh_f = (const float*)d_in[2];
    const float* bih_f = (const float*)d_in[3];
    const float* bhh_f = (const float*)d_in[4];
    const float* wih_b = (const float*)d_in[5];
    const float* whh_b = (const float*)d_in[6];
    const float* bih_b = (const float*)d_in[7];
    const float* bhh_b = (const float*)d_in[8];

    char* ws = (char*)d_ws;
    u64* hfrag  = (u64*)(ws + HFRAG_OFF);
    float* xhat = (float*)(ws + XHAT_OFF);
    u64* xs     = (u64*)(ws + XS_OFF);

    lstm_persistent<<<NBLK, 256, 0, stream>>>(
        u, wih_f, whh_f, bih_f, bhh_f, wih_b, whh_b, bih_b, bhh_b,
        hfrag, xhat, xs);

    const int n4 = BB * TT * DD / 4;
    epilogue<<<n4 / 256, 256, 0, stream>>>(u, xhat, (float*)d_out);
}